// Round 1
// baseline (672.516 us; speedup 1.0000x reference)
//
#include <hip/hip_runtime.h>

typedef short bf16x8 __attribute__((ext_vector_type(8)));
typedef float f32x4  __attribute__((ext_vector_type(4)));

#define MFMA(A, B, C) __builtin_amdgcn_mfma_f32_16x16x32_bf16(A, B, C, 0, 0, 0)

__device__ __forceinline__ short f2b(float f) {
  union { float f; unsigned u; } v; v.f = f;
  unsigned r = v.u + 0x7fffu + ((v.u >> 16) & 1u);   // RNE float->bf16
  return (short)(r >> 16);
}

#define NTOK 49
#define CDIM 128
#define SCALE 0.17677669529663687f   // 32^-0.5

// strides in bf16 elements (rows 16B-aligned, bank-uniform for ds_read_b128)
#define XS_STR 136
#define PS_STR 72
#define VT_STR 72

// LDS layout (bytes). Total 58416 (< 64KB -> 2 blocks/CU).
// Live sets: phaseA {xs,qs,ks,vt}; phaseB {msk,bia (alias xs), qs,ks,vt};
// ps (36864) aliases xs+qs+part-of-ks after softmax barrier; os aliases ps h0.
#define XS_OFF   0          // 49*136*2 = 13328
#define QS_OFF   13328
#define KS_OFF   26656
#define VT_OFF   39984      // 128*72*2 = 18432 (zero-padded tokens)
#define LDS_TOTAL 58416
#define MSK_OFF  0          // 2401 f32 (phase B only)
#define BIA_OFF  9616       // 676 f32
#define PS_OFF   0          // 4 * 64*72*2 = 36864
#define OS_OFF   0          // 49*136*2

extern "C" __global__ void winattn_prep(const float* __restrict__ qw,
                                        const float* __restrict__ pw,
                                        short* __restrict__ wq, short* __restrict__ wp) {
  const int i = blockIdx.x * 256 + threadIdx.x;
  if (i < 384 * 128) wq[i] = f2b(qw[i]);
  if (i < 128 * 128) wp[i] = f2b(pw[i]);
}

extern "C" __global__ void __launch_bounds__(256, 2)
winattn_main(const float* __restrict__ x, const float* __restrict__ mask,
             const float* __restrict__ qkv_b, const float* __restrict__ proj_b,
             const float* __restrict__ bias_table,
             const short* __restrict__ wq, const short* __restrict__ wp,
             float* __restrict__ out)
{
  extern __shared__ char lds[];
  short* xs  = (short*)(lds + XS_OFF);
  short* qs  = (short*)(lds + QS_OFF);
  short* ks  = (short*)(lds + KS_OFF);
  short* vt  = (short*)(lds + VT_OFF);
  float* msk = (float*)(lds + MSK_OFF);
  float* bia = (float*)(lds + BIA_OFF);
  short* ps  = (short*)(lds + PS_OFF);
  short* os  = (short*)(lds + OS_OFF);

  const int tid  = threadIdx.x;
  const int blk  = blockIdx.x;
  const int wi   = blk & 63;          // window-mask index: b % nW
  const int wave = tid >> 6;
  const int lane = tid & 63;
  const int m    = lane & 15;
  const int quad = lane >> 4;

  // ---------------- init: zero vt (pad tokens must be 0), stage x -> bf16 LDS
  {
    int* vz = (int*)vt;
    #pragma unroll
    for (int i = 0; i < 18; ++i) vz[tid + i * 256] = 0;   // 4608 dwords
    const float4* xg = (const float4*)(x + (size_t)blk * (NTOK * CDIM));
    for (int i = tid; i < NTOK * 32; i += 256) {
      float4 v = xg[i];
      int row = i >> 5, c4 = (i & 31) << 2;
      int lo = (f2b(v.x) & 0xffff) | ((int)f2b(v.y) << 16);
      int hi = (f2b(v.z) & 0xffff) | ((int)f2b(v.w) << 16);
      int* d = (int*)&xs[row * XS_STR + c4];
      d[0] = lo; d[1] = hi;
    }
  }
  __syncthreads();

  // ---------------- phase A: qkv = x @ qkv_w^T + qkv_b  (M=64pad, N=384, K=128)
  {
    bf16x8 ax[4][4];
    #pragma unroll
    for (int mt = 0; mt < 4; ++mt)
      #pragma unroll
      for (int kk = 0; kk < 4; ++kk)
        ax[mt][kk] = *(const bf16x8*)&xs[(mt * 16 + m) * XS_STR + kk * 32 + quad * 8];

    for (int t = 0; t < 6; ++t) {                 // wave owns 6 n-tiles
      const int nt = wave * 6 + t;
      const int n  = nt * 16 + m;
      const short* wr = wq + n * CDIM + quad * 8;
      bf16x8 bw[4];
      #pragma unroll
      for (int kk = 0; kk < 4; ++kk) bw[kk] = *(const bf16x8*)(wr + kk * 32);
      f32x4 acc[4] = {};
      #pragma unroll
      for (int kk = 0; kk < 4; ++kk)
        #pragma unroll
        for (int mt = 0; mt < 4; ++mt)
          acc[mt] = MFMA(ax[mt][kk], bw[kk], acc[mt]);
      const float bb = qkv_b[n];
      #pragma unroll
      for (int mt = 0; mt < 4; ++mt)
        #pragma unroll
        for (int r = 0; r < 4; ++r) {
          const int row = mt * 16 + quad * 4 + r;
          if (row < NTOK) {
            const short bv = f2b(acc[mt][r] + bb);
            if (n < 128)      qs[row * XS_STR + n] = bv;
            else if (n < 256) ks[row * XS_STR + (n - 128)] = bv;
            else              vt[(n - 256) * VT_STR + row] = bv;  // v stored transposed
          }
        }
    }
  }
  __syncthreads();

  // stage mask window + bias table into dead xs region; prefetch q/k fragments
  {
    const float* mw = mask + (size_t)wi * (NTOK * NTOK);
    for (int i = tid; i < NTOK * NTOK; i += 256) msk[i] = mw[i];
    for (int i = tid; i < 169 * 4; i += 256) bia[i] = bias_table[i];
  }
  const int h = wave;                               // wave == head
  bf16x8 aq[4], bk[4];
  #pragma unroll
  for (int mt = 0; mt < 4; ++mt)
    aq[mt] = *(const bf16x8*)&qs[(mt * 16 + m) * XS_STR + h * 32 + quad * 8];
  #pragma unroll
  for (int nt = 0; nt < 4; ++nt)
    bk[nt] = *(const bf16x8*)&ks[(nt * 16 + m) * XS_STR + h * 32 + quad * 8];
  __syncthreads();

  // ---------------- phase B: S = q k^T (K=32, one MFMA/tile), bias+mask, softmax
  f32x4 sac[4][4] = {};
  #pragma unroll
  for (int mt = 0; mt < 4; ++mt)
    #pragma unroll
    for (int nt = 0; nt < 4; ++nt)
      sac[mt][nt] = MFMA(aq[mt], bk[nt], sac[mt][nt]);

  float rinv[4][4];
  #pragma unroll
  for (int mt = 0; mt < 4; ++mt) {
    #pragma unroll
    for (int r = 0; r < 4; ++r) {
      const int row = mt * 16 + quad * 4 + r;
      const int rh = (int)((unsigned)row / 7u), rw = row - rh * 7;
      float sv[4];
      #pragma unroll
      for (int nt = 0; nt < 4; ++nt) {
        const int c = nt * 16 + m;
        if (c < NTOK) {
          const int ch = (int)((unsigned)c / 7u), cw = c - ch * 7;
          const int idx = (rh - ch + 6) * 13 + (rw - cw + 6);
          sv[nt] = sac[mt][nt][r] * SCALE + msk[row * NTOK + c] + bia[idx * 4 + h];
        } else sv[nt] = -1e30f;                    // padded keys -> weight 0
      }
      float mx = fmaxf(fmaxf(sv[0], sv[1]), fmaxf(sv[2], sv[3]));
      #pragma unroll
      for (int d = 1; d < 16; d <<= 1) mx = fmaxf(mx, __shfl_xor(mx, d));
      float sum = 0.f;
      #pragma unroll
      for (int nt = 0; nt < 4; ++nt) {
        const float p = __expf(sv[nt] - mx);       // unnormalized; 1/sum folded into O
        sac[mt][nt][r] = p; sum += p;
      }
      #pragma unroll
      for (int d = 1; d < 16; d <<= 1) sum += __shfl_xor(sum, d);
      rinv[mt][r] = 1.f / sum;
    }
  }
  __syncthreads();   // all q/k/mask reads done -> ps may overwrite those regions

  short* psh = ps + h * (64 * PS_STR);
  #pragma unroll
  for (int mt = 0; mt < 4; ++mt)
    #pragma unroll
    for (int r = 0; r < 4; ++r) {
      const int row = mt * 16 + quad * 4 + r;
      #pragma unroll
      for (int nt = 0; nt < 4; ++nt)
        psh[row * PS_STR + nt * 16 + m] = f2b(sac[mt][nt][r]);
    }
  __syncthreads();

  // ---------------- phase C: O = P @ V (K=64pad; vt pad tokens are zero)
  f32x4 oacc[4][2] = {};
  #pragma unroll
  for (int k2 = 0; k2 < 2; ++k2) {
    bf16x8 bv0 = *(const bf16x8*)&vt[(h * 32 + m) * VT_STR + k2 * 32 + quad * 8];
    bf16x8 bv1 = *(const bf16x8*)&vt[(h * 32 + 16 + m) * VT_STR + k2 * 32 + quad * 8];
    #pragma unroll
    for (int mt = 0; mt < 4; ++mt) {
      bf16x8 pa = *(const bf16x8*)&psh[(mt * 16 + m) * PS_STR + k2 * 32 + quad * 8];
      oacc[mt][0] = MFMA(pa, bv0, oacc[mt][0]);
      oacc[mt][1] = MFMA(pa, bv1, oacc[mt][1]);
    }
  }
  __syncthreads();   // all ps reads done -> os may overwrite
  #pragma unroll
  for (int mt = 0; mt < 4; ++mt)
    #pragma unroll
    for (int r = 0; r < 4; ++r) {
      const int row = mt * 16 + quad * 4 + r;
      if (row < NTOK) {
        os[row * XS_STR + h * 32 + m]      = f2b(oacc[mt][0][r] * rinv[mt][r]);
        os[row * XS_STR + h * 32 + 16 + m] = f2b(oacc[mt][1][r] * rinv[mt][r]);
      }
    }
  __syncthreads();

  // ---------------- phase D: out = O @ proj_w^T + proj_b, fp32 store
  {
    bf16x8 ao[4][4];
    #pragma unroll
    for (int mt = 0; mt < 4; ++mt)
      #pragma unroll
      for (int kk = 0; kk < 4; ++kk)
        ao[mt][kk] = *(const bf16x8*)&os[(mt * 16 + m) * XS_STR + kk * 32 + quad * 8];
    float* outb = out + (size_t)blk * (NTOK * CDIM);
    #pragma unroll
    for (int t = 0; t < 2; ++t) {
      const int n = (wave * 2 + t) * 16 + m;
      const short* wr = wp + n * CDIM + quad * 8;
      bf16x8 bw[4];
      #pragma unroll
      for (int kk = 0; kk < 4; ++kk) bw[kk] = *(const bf16x8*)(wr + kk * 32);
      f32x4 acc[4] = {};
      #pragma unroll
      for (int kk = 0; kk < 4; ++kk)
        #pragma unroll
        for (int mt = 0; mt < 4; ++mt)
          acc[mt] = MFMA(ao[mt][kk], bw[kk], acc[mt]);
      const float pb = proj_b[n];
      #pragma unroll
      for (int mt = 0; mt < 4; ++mt)
        #pragma unroll
        for (int r = 0; r < 4; ++r) {
          const int row = mt * 16 + quad * 4 + r;
          if (row < NTOK) outb[row * CDIM + n] = acc[mt][r] + pb;
        }
    }
  }
}

extern "C" void kernel_launch(void* const* d_in, const int* in_sizes, int n_in,
                              void* d_out, int out_size, void* d_ws, size_t ws_size,
                              hipStream_t stream)
{
  const float* x          = (const float*)d_in[0];
  const float* mask       = (const float*)d_in[1];
  const float* qkv_w      = (const float*)d_in[2];
  const float* qkv_b      = (const float*)d_in[3];
  const float* proj_w     = (const float*)d_in[4];
  const float* proj_b     = (const float*)d_in[5];
  const float* bias_table = (const float*)d_in[6];

  short* wq = (short*)d_ws;              // 384*128 bf16
  short* wp = wq + 384 * 128;            // 128*128 bf16

  winattn_prep<<<192, 256, 0, stream>>>(qkv_w, proj_w, wq, wp);
  winattn_main<<<8192, 256, LDS_TOTAL, stream>>>(x, mask, qkv_b, proj_b, bias_table,
                                                 wq, wp, (float*)d_out);
}